// Round 7
// baseline (499.127 us; speedup 1.0000x reference)
//
#include <hip/hip_runtime.h>

// LSTM B=256, T=1024, I=64, H=128. One block/batch row (256 blocks = 256 CUs).
// R15 = R13 (builtin i8 h-GEMM) minus the next-chunk spread machinery.
//  - Spill forensics: R12/R13 scratch = 242MB/dispatch = ~7 dwords/thread/
//    chunk-iter -> only ~8-16 regs over the 128 arch budget. R10's f16
//    B-fragments (96 regs) ride in AGPRs; i8 bqh (32) stays arch-side, so
//    arch demand = ~104 + 32 = ~136. Fix: free 24 arch regs by dropping
//    nax/nxw (next-chunk xw spread) and computing the chunk-GEMM at chunk
//    top from prefetched xf (R8 structure). Costs the ~11us chunk-lump R9
//    recovered; clears ~240MB/dispatch of spill traffic.
//  - R14's inline-asm MFMA (NaN: untied D/C + unmodeled asm hazards) reverted;
//    builtins only.
//  - i8 path unchanged: h quantized at fixed scale 127 (|h|<1), LDS bytes,
//    2x ds_read_b128/step; W_hh per-row max-abs i8, lane-local dequant with
//    exp2 consts folded; c/activations f32; x-projection f16 MFMA.

typedef _Float16 half8  __attribute__((ext_vector_type(8)));
typedef _Float16 half2t __attribute__((ext_vector_type(2)));
typedef float  floatx4  __attribute__((ext_vector_type(4)));
typedef int    intx4   __attribute__((ext_vector_type(4)));

constexpr int Tt = 1024;
constexpr int Ii = 64;
constexpr int Hh = 128;
constexpr int CH = 16;          // timesteps per x chunk-GEMM
constexpr int NCH = Tt / CH;    // 64 chunks

__device__ __forceinline__ float fast_rcp(float x) { return __builtin_amdgcn_rcpf(x); }
__device__ __forceinline__ float exp2_(float x)    { return __builtin_amdgcn_exp2f(x); }
__device__ __forceinline__ half2t pk16(float a, float b) {
    return __builtin_bit_cast(half2t, __builtin_amdgcn_cvt_pkrtz(a, b));
}
#define MFMA16(A, B, C) __builtin_amdgcn_mfma_f32_16x16x32_f16((A), (B), (C), 0, 0, 0)
#define MFMAI8(A, B, C) __builtin_amdgcn_mfma_i32_16x16x64_i8((A), (B), (C), 0, 0, 0)
union H8U { half8 v; half2t p[4]; };

__device__ __forceinline__ half8 cvt8(float4 a, float4 b) {
    H8U u;
    u.p[0] = pk16(a.x, a.y); u.p[1] = pk16(a.z, a.w);
    u.p[2] = pk16(b.x, b.y); u.p[3] = pk16(b.z, b.w);
    return u.v;
}
__device__ __forceinline__ floatx4 splat4(float a) { floatx4 r = {a, a, a, a}; return r; }

// register-only i8x4 pack: low byte = s[0] (little-endian, matches LDS bytes)
__device__ __forceinline__ int pkq4(const float* s, float qs) {
    const int a = (int)rintf(s[0] * qs) & 255;
    const int b = (int)rintf(s[1] * qs) & 255;
    const int c = (int)rintf(s[2] * qs) & 255;
    const int d = (int)rintf(s[3] * qs) & 255;
    return a | (b << 8) | (c << 16) | (d << 24);
}

__global__
__attribute__((amdgpu_flat_work_group_size(512, 512), amdgpu_waves_per_eu(2, 2)))
void lstm_mfma11(
    const float* __restrict__ data,   // [B, T, I]
    const float* __restrict__ W_ih,   // [4H, I]
    const float* __restrict__ W_hh,   // [4H, H]
    const float* __restrict__ b_ih,   // [4H]
    const float* __restrict__ b_hh,   // [4H]
    float* __restrict__ out)          // [B, T, H] f32
{
    const int b   = blockIdx.x;
    const int t   = threadIdx.x;
    const int w   = t >> 6;    // wave 0..7
    const int l   = t & 63;    // lane
    const int col = l & 15;    // N-col == hidden unit offset within wave's 16
    const int kg  = l >> 4;    // k-group / C-row group

    // ---- weights static in registers ----
    // gates 0(i),1(f),3(o): sigma(x)=rcp(1+exp2(-log2e*x))
    // gate 2(g):            tanh(x) via e=exp2(-2log2e*x), (1-e)*rcp(1+e)
    intx4 bqh[4][2];   // Whh int8: 4 gates x 2 K-slices (K=128 as 2x64)
    float dqh[4];      // per-gate-row dequant scale (sc folded)
    half8 bfx[4][2];   // Wih f16 (sc folded): 4 gates x 2 K-slices (K=64)
    float bs[4];       // scaled bias (x chunk-GEMM C-init)
#pragma unroll
    for (int g = 0; g < 4; ++g) {
        const float sc = (g == 2) ? -2.8853900817779268f : -1.4426950408889634f;
        const int row = 128 * g + 16 * w + col;
        bs[g] = sc * (b_ih[row] + b_hh[row]);
        const float* wh = W_hh + (size_t)row * Hh;
        const float* wi = W_ih + (size_t)row * Ii;
        // pass 1: row max-abs
        float mw = 1e-20f;
#pragma unroll
        for (int k = 0; k < Hh; k += 4) {
            const float4 f = *(const float4*)(wh + k);
            mw = fmaxf(mw, fmaxf(fmaxf(fabsf(f.x), fabsf(f.y)),
                                 fmaxf(fabsf(f.z), fabsf(f.w))));
        }
        const float qs = 127.f / mw;
        dqh[g] = sc * mw * (1.f / (127.f * 127.f));
        // pass 2: quantize this lane's 2 x 16-byte B fragments (register-only)
#pragma unroll
        for (int s = 0; s < 2; ++s) {
            const float* src = wh + 64 * s + 16 * kg;
            intx4 q;
            q[0] = pkq4(src + 0,  qs);
            q[1] = pkq4(src + 4,  qs);
            q[2] = pkq4(src + 8,  qs);
            q[3] = pkq4(src + 12, qs);
            bqh[g][s] = q;
        }
        // x-projection weights stay f16 with sc folded
#pragma unroll
        for (int s = 0; s < 2; ++s) {
            const float* src = wi + 32 * s + 8 * kg;
            const float4 f0 = ((const float4*)src)[0];
            const float4 f1 = ((const float4*)src)[1];
            H8U u;
            u.p[0] = pk16(sc * f0.x, sc * f0.y); u.p[1] = pk16(sc * f0.z, sc * f0.w);
            u.p[2] = pk16(sc * f1.x, sc * f1.y); u.p[3] = pk16(sc * f1.z, sc * f1.w);
            bfx[g][s] = u.v;
        }
    }

    __shared__ __align__(16) signed char hbq[2][Hh];  // h i8 double buffer

    const float* xp  = data + (size_t)b * Tt * Ii;
    float*       opr = out  + (size_t)b * Tt * Hh + 16 * w + col;

    if (t < Hh) hbq[0][t] = 0;        // h0 = 0

    // x chunk staging: lane reads x[t0 + (l&15)][32*s2 + 8*kg + j], j=0..7
    const float* xbase = xp + (size_t)(l & 15) * Ii + 8 * kg;
    float4 xf0 = *(const float4*)(xbase);
    float4 xf1 = *(const float4*)(xbase + 4);
    float4 xf2 = *(const float4*)(xbase + 32);
    float4 xf3 = *(const float4*)(xbase + 36);

    float c = 0.0f;
    __syncthreads();   // h0 visible (one full drain, outside the loop)

#pragma unroll 1
    for (int n = 0; n < NCH; ++n) {
        // ---- chunk-GEMM: xw[g] rows = sc*(xW+bias) for steps t0..t0+15 ----
        half8 ax0 = cvt8(xf0, xf1);
        half8 ax1 = cvt8(xf2, xf3);
        floatx4 xw0 = MFMA16(ax0, bfx[0][0], splat4(bs[0]));
        floatx4 xw1 = MFMA16(ax0, bfx[1][0], splat4(bs[1]));
        floatx4 xw2 = MFMA16(ax0, bfx[2][0], splat4(bs[2]));
        floatx4 xw3 = MFMA16(ax0, bfx[3][0], splat4(bs[3]));
        xw0 = MFMA16(ax1, bfx[0][1], xw0);
        xw1 = MFMA16(ax1, bfx[1][1], xw1);
        xw2 = MFMA16(ax1, bfx[2][1], xw2);
        xw3 = MFMA16(ax1, bfx[3][1], xw3);

        // ---- prefetch next chunk's x (in flight across ~16 steps) ----
        {
            const int nn = (n + 1 < NCH) ? (n + 1) : n;
            const float* xb2 = xbase + (size_t)nn * CH * Ii;
            xf0 = *(const float4*)(xb2);
            xf1 = *(const float4*)(xb2 + 4);
            xf2 = *(const float4*)(xb2 + 32);
            xf3 = *(const float4*)(xb2 + 36);
        }

        // step s = 16n + 4P + R; h buffer parity = R&1 (16n+4P even).
        // f,g,i 2-deep i8 chains first; o trails so the exposed tail is just
        // sigma(o)*tc + quant/pack/write.
#define STEP(P, R, CUR, XTRA)                                                 \
        {                                                                     \
            const signed char* hbase = &hbq[CUR][16 * kg];                    \
            const intx4 ah0 = *(const intx4*)(hbase);                         \
            const intx4 ah1 = *(const intx4*)(hbase + 64);                    \
            XTRA;                                                             \
            __builtin_amdgcn_s_setprio(1);                                    \
            const intx4 z4 = {0, 0, 0, 0};                                    \
            intx4 qf = MFMAI8(ah0, bqh[1][0], z4);   /* f */                  \
            intx4 qg = MFMAI8(ah0, bqh[2][0], z4);   /* g */                  \
            intx4 qi = MFMAI8(ah0, bqh[0][0], z4);   /* i */                  \
            qf = MFMAI8(ah1, bqh[1][1], qf);                                  \
            qg = MFMAI8(ah1, bqh[2][1], qg);                                  \
            qi = MFMAI8(ah1, bqh[0][1], qi);                                  \
            intx4 qo = MFMAI8(ah0, bqh[3][0], z4);   /* o */                  \
            const float fg = fast_rcp(1.0f + exp2_(fmaf((float)qf[R], dqh[1], xw1[R]))); \
            const float eg = exp2_(fmaf((float)qg[R], dqh[2], xw2[R]));       \
            qo = MFMAI8(ah1, bqh[3][1], qo);                                  \
            const float fc = fg * c;                                          \
            const float gv = (1.0f - eg) * fast_rcp(1.0f + eg);               \
            const float ig = fast_rcp(1.0f + exp2_(fmaf((float)qi[R], dqh[0], xw0[R]))); \
            __builtin_amdgcn_s_setprio(0);                                    \
            c = fmaf(ig, gv, fc);                                             \
            const float ec = exp2_(-2.8853900817779268f * c);                 \
            const float tc = (1.0f - ec) * fast_rcp(1.0f + ec);               \
            const float og = fast_rcp(1.0f + exp2_(fmaf((float)qo[R], dqh[3], xw3[R]))); \
            const float h  = og * tc;                                         \
            if (kg == (P)) {                                                  \
                hbq[(CUR) ^ 1][16 * w + col] =                                \
                    (signed char)(int)rintf(h * 127.f);                       \
                *opr = h;                                                     \
            }                                                                 \
            opr += Hh;                                                        \
            asm volatile("s_waitcnt lgkmcnt(0)\n\ts_barrier" ::: "memory");   \
        }

        // phase P handles steps 4P..4P+3; c lineage hops lane-groups:
        // rotate c from group P-1 (or prev chunk's group 3) into group P.
        // Rotation rides the R==0 XTRA slot (after the ds_read issues).
#define PHASE(P)                                                              \
        STEP(P, 0, 0, c = __shfl(c, (l + 48) & 63))                           \
        STEP(P, 1, 1, (void)0) STEP(P, 2, 0, (void)0) STEP(P, 3, 1, (void)0)

        PHASE(0) PHASE(1) PHASE(2) PHASE(3)
#undef PHASE
#undef STEP
    }
}

extern "C" void kernel_launch(void* const* d_in, const int* in_sizes, int n_in,
                              void* d_out, int out_size, void* d_ws, size_t ws_size,
                              hipStream_t stream) {
    const float* data = (const float*)d_in[0];
    const float* W_ih = (const float*)d_in[1];
    const float* W_hh = (const float*)d_in[2];
    const float* b_ih = (const float*)d_in[3];
    const float* b_hh = (const float*)d_in[4];
    float* out = (float*)d_out;

    hipLaunchKernelGGL(lstm_mfma11, dim3(256), dim3(512), 0, stream,
                       data, W_ih, W_hh, b_ih, b_hh, out);
}

// Round 8
// 465.193 us; speedup vs baseline: 1.0729x; 1.0729x over previous
//
#include <hip/hip_runtime.h>

// LSTM B=256, T=1024, I=64, H=128. One block/batch row (256 blocks = 256 CUs).
// R16: split x-projection OUT of the recurrence loop via d_ws staging.
//  - R11-R15: i8 h-GEMM halves MFMA issue (~250cyc/step, proven) but drowns
//    in ~240MB/dispatch scratch; 3 rounds of register surgery non-responsive
//    (VGPR_Count pinned 128). Fix: remove the x-path register footprint from
//    the loop entirely.
//  - Phase A (per block): f16 chunk-GEMM computes scaled preacts XW for all
//    64 chunks; each lane stores ITS OWN 16-half fragment (32B, coalesced)
//    to d_ws. Identity layout: consumer lane == producer lane, so phase B
//    reads back exactly what the same lane wrote (vmcnt-ordered, no fence).
//  - Phase B: lean i8 recurrence. Per step: 2x ds_read_b128 (h i8) + 8x
//    mfma_i32_16x16x64_i8 + activations; per chunk: one 32B ws load
//    (prefetched). Arch demand ~105 regs, no AGPR pressure, no spill.
//  - Fallback: if ws_size < 268MB, launch the verified R10 f16 kernel.
//  - i8 numerics unchanged from R13/R15 (passed, absmax 0.0039): h at fixed
//    scale 127, W_hh per-row max-abs, lane-local dequant, exp2 consts folded.

typedef _Float16 half8  __attribute__((ext_vector_type(8)));
typedef _Float16 half16 __attribute__((ext_vector_type(16)));
typedef _Float16 half2t __attribute__((ext_vector_type(2)));
typedef float  floatx4  __attribute__((ext_vector_type(4)));
typedef int    intx4   __attribute__((ext_vector_type(4)));

constexpr int Tt = 1024;
constexpr int Ii = 64;
constexpr int Hh = 128;
constexpr int CH = 16;          // timesteps per x chunk-GEMM
constexpr int NCH = Tt / CH;    // 64 chunks

__device__ __forceinline__ float fast_rcp(float x) { return __builtin_amdgcn_rcpf(x); }
__device__ __forceinline__ float exp2_(float x)    { return __builtin_amdgcn_exp2f(x); }
__device__ __forceinline__ half2t pk16(float a, float b) {
    return __builtin_bit_cast(half2t, __builtin_amdgcn_cvt_pkrtz(a, b));
}
#define MFMA16(A, B, C) __builtin_amdgcn_mfma_f32_16x16x32_f16((A), (B), (C), 0, 0, 0)
#define MFMAI8(A, B, C) __builtin_amdgcn_mfma_i32_16x16x64_i8((A), (B), (C), 0, 0, 0)
union H8U { half8 v; half2t p[4]; };

__device__ __forceinline__ half8 cvt8(float4 a, float4 b) {
    H8U u;
    u.p[0] = pk16(a.x, a.y); u.p[1] = pk16(a.z, a.w);
    u.p[2] = pk16(b.x, b.y); u.p[3] = pk16(b.z, b.w);
    return u.v;
}
__device__ __forceinline__ floatx4 splat4(float a) { floatx4 r = {a, a, a, a}; return r; }

// register-only i8x4 pack: low byte = s[0] (little-endian, matches LDS bytes)
__device__ __forceinline__ int pkq4(const float* s, float qs) {
    const int a = (int)rintf(s[0] * qs) & 255;
    const int b = (int)rintf(s[1] * qs) & 255;
    const int c = (int)rintf(s[2] * qs) & 255;
    const int d = (int)rintf(s[3] * qs) & 255;
    return a | (b << 8) | (c << 16) | (d << 24);
}

// ============================ R16 main kernel ============================
__global__
__attribute__((amdgpu_flat_work_group_size(512, 512), amdgpu_waves_per_eu(2, 2)))
void lstm_ws16(
    const float* __restrict__ data,   // [B, T, I]
    const float* __restrict__ W_ih,   // [4H, I]
    const float* __restrict__ W_hh,   // [4H, H]
    const float* __restrict__ b_ih,   // [4H]
    const float* __restrict__ b_hh,   // [4H]
    float* __restrict__ out,          // [B, T, H] f32
    _Float16* __restrict__ ws)        // [B][NCH][512 lanes][16] f16 preacts
{
    const int b   = blockIdx.x;
    const int t   = threadIdx.x;
    const int w   = t >> 6;    // wave 0..7
    const int l   = t & 63;    // lane
    const int col = l & 15;    // N-col == hidden unit offset within wave's 16
    const int kg  = l >> 4;    // k-group / C-row group

    __shared__ __align__(16) signed char hbq[2][Hh];  // h i8 double buffer
    if (t < Hh) hbq[0][t] = 0;        // h0 = 0

    // per-lane ws slot: identity producer/consumer layout, 16 halfs = 32B
    _Float16* wsl = ws + (((size_t)b * NCH) * 512 + (size_t)t) * 16;

    // gates 0(i),1(f),3(o): sigma(x)=rcp(1+exp2(-log2e*x))
    // gate 2(g):            tanh(x) via e=exp2(-2log2e*x), (1-e)*rcp(1+e)

    // ---------------- Phase A: XW preacts -> ws (f16) ----------------
    {
        half8 bfx[4][2];   // Wih f16, sc folded
        float bs[4];       // scaled bias
#pragma unroll
        for (int g = 0; g < 4; ++g) {
            const float sc = (g == 2) ? -2.8853900817779268f : -1.4426950408889634f;
            const int row = 128 * g + 16 * w + col;
            bs[g] = sc * (b_ih[row] + b_hh[row]);
            const float* wi = W_ih + (size_t)row * Ii;
#pragma unroll
            for (int s = 0; s < 2; ++s) {
                const float* src = wi + 32 * s + 8 * kg;
                const float4 f0 = ((const float4*)src)[0];
                const float4 f1 = ((const float4*)src)[1];
                H8U u;
                u.p[0] = pk16(sc * f0.x, sc * f0.y); u.p[1] = pk16(sc * f0.z, sc * f0.w);
                u.p[2] = pk16(sc * f1.x, sc * f1.y); u.p[3] = pk16(sc * f1.z, sc * f1.w);
                bfx[g][s] = u.v;
            }
        }
        const float* xbase = data + (size_t)b * Tt * Ii + (size_t)(l & 15) * Ii + 8 * kg;
#pragma unroll 1
        for (int n = 0; n < NCH; ++n) {
            const float* xb = xbase + (size_t)n * CH * Ii;
            const float4 f0 = *(const float4*)(xb);
            const float4 f1 = *(const float4*)(xb + 4);
            const float4 f2 = *(const float4*)(xb + 32);
            const float4 f3 = *(const float4*)(xb + 36);
            const half8 ax0 = cvt8(f0, f1);
            const half8 ax1 = cvt8(f2, f3);
            floatx4 x0 = MFMA16(ax0, bfx[0][0], splat4(bs[0]));
            floatx4 x1 = MFMA16(ax0, bfx[1][0], splat4(bs[1]));
            floatx4 x2 = MFMA16(ax0, bfx[2][0], splat4(bs[2]));
            floatx4 x3 = MFMA16(ax0, bfx[3][0], splat4(bs[3]));
            x0 = MFMA16(ax1, bfx[0][1], x0);
            x1 = MFMA16(ax1, bfx[1][1], x1);
            x2 = MFMA16(ax1, bfx[2][1], x2);
            x3 = MFMA16(ax1, bfx[3][1], x3);
            half16 vh;
#pragma unroll
            for (int R = 0; R < 4; ++R) {
                vh[0 * 4 + R] = (_Float16)x0[R];
                vh[1 * 4 + R] = (_Float16)x1[R];
                vh[2 * 4 + R] = (_Float16)x2[R];
                vh[3 * 4 + R] = (_Float16)x3[R];
            }
            *(half16*)(wsl + (size_t)n * 512 * 16) = vh;
        }
    }
    // same-lane RAW on ws: drain vmem before phase B reads it back
    asm volatile("s_waitcnt vmcnt(0)" ::: "memory");

    // ---------------- Phase B: i8 recurrence ----------------
    intx4 bqh[4][2];   // Whh int8: 4 gates x 2 K-slices (K=128 as 2x64)
    float dqh[4];      // per-gate-row dequant scale (sc folded)
#pragma unroll
    for (int g = 0; g < 4; ++g) {
        const float sc = (g == 2) ? -2.8853900817779268f : -1.4426950408889634f;
        const int row = 128 * g + 16 * w + col;
        const float* wh = W_hh + (size_t)row * Hh;
        float mw = 1e-20f;
#pragma unroll
        for (int k = 0; k < Hh; k += 4) {
            const float4 f = *(const float4*)(wh + k);
            mw = fmaxf(mw, fmaxf(fmaxf(fabsf(f.x), fabsf(f.y)),
                                 fmaxf(fabsf(f.z), fabsf(f.w))));
        }
        const float qs = 127.f / mw;
        dqh[g] = sc * mw * (1.f / (127.f * 127.f));
#pragma unroll
        for (int s = 0; s < 2; ++s) {
            const float* src = wh + 64 * s + 16 * kg;
            intx4 q;
            q[0] = pkq4(src + 0,  qs);
            q[1] = pkq4(src + 4,  qs);
            q[2] = pkq4(src + 8,  qs);
            q[3] = pkq4(src + 12, qs);
            bqh[g][s] = q;
        }
    }

    float* opr = out + (size_t)b * Tt * Hh + 16 * w + col;

    half16 cw = *(const half16*)(wsl);   // chunk 0 preacts
    half16 nw;

    float c = 0.0f;
    __syncthreads();   // h0 visible (one full drain, outside the loop)

#pragma unroll 1
    for (int n = 0; n < NCH; ++n) {
        {
            const int nn = (n + 1 < NCH) ? (n + 1) : n;
            nw = *(const half16*)(wsl + (size_t)nn * 512 * 16);
        }

        // step s = 16n + 4P + R; h buffer parity = R&1 (16n+4P even).
        // f,g,i 2-deep i8 chains first; o trails so the exposed tail is just
        // sigma(o)*tc + quant/pack/write.
#define STEP(P, R, CUR, XTRA)                                                 \
        {                                                                     \
            const signed char* hbase = &hbq[CUR][16 * kg];                    \
            const intx4 ah0 = *(const intx4*)(hbase);                         \
            const intx4 ah1 = *(const intx4*)(hbase + 64);                    \
            XTRA;                                                             \
            __builtin_amdgcn_s_setprio(1);                                    \
            const intx4 z4 = {0, 0, 0, 0};                                    \
            intx4 qf = MFMAI8(ah0, bqh[1][0], z4);   /* f */                  \
            intx4 qg = MFMAI8(ah0, bqh[2][0], z4);   /* g */                  \
            intx4 qi = MFMAI8(ah0, bqh[0][0], z4);   /* i */                  \
            qf = MFMAI8(ah1, bqh[1][1], qf);                                  \
            qg = MFMAI8(ah1, bqh[2][1], qg);                                  \
            qi = MFMAI8(ah1, bqh[0][1], qi);                                  \
            intx4 qo = MFMAI8(ah0, bqh[3][0], z4);   /* o */                  \
            const float fg = fast_rcp(1.0f + exp2_(fmaf((float)qf[R], dqh[1], (float)cw[4 + (R)]))); \
            const float eg = exp2_(fmaf((float)qg[R], dqh[2], (float)cw[8 + (R)])); \
            qo = MFMAI8(ah1, bqh[3][1], qo);                                  \
            const float fc = fg * c;                                          \
            const float gv = (1.0f - eg) * fast_rcp(1.0f + eg);               \
            const float ig = fast_rcp(1.0f + exp2_(fmaf((float)qi[R], dqh[0], (float)cw[0 + (R)]))); \
            __builtin_amdgcn_s_setprio(0);                                    \
            c = fmaf(ig, gv, fc);                                             \
            const float ec = exp2_(-2.8853900817779268f * c);                 \
            const float tc = (1.0f - ec) * fast_rcp(1.0f + ec);               \
            const float og = fast_rcp(1.0f + exp2_(fmaf((float)qo[R], dqh[3], (float)cw[12 + (R)]))); \
            const float h  = og * tc;                                         \
            if (kg == (P)) {                                                  \
                hbq[(CUR) ^ 1][16 * w + col] =                                \
                    (signed char)(int)rintf(h * 127.f);                       \
                *opr = h;                                                     \
            }                                                                 \
            opr += Hh;                                                        \
            asm volatile("s_waitcnt lgkmcnt(0)\n\ts_barrier" ::: "memory");   \
        }

        // phase P handles steps 4P..4P+3; c lineage hops lane-groups:
        // rotate c from group P-1 (or prev chunk's group 3) into group P.
#define PHASE(P)                                                              \
        STEP(P, 0, 0, c = __shfl(c, (l + 48) & 63))                           \
        STEP(P, 1, 1, (void)0) STEP(P, 2, 0, (void)0) STEP(P, 3, 1, (void)0)

        PHASE(0) PHASE(1) PHASE(2) PHASE(3)
#undef PHASE
#undef STEP

        cw = nw;
    }
}

// ====================== fallback: verified R10 kernel ======================
__global__ __launch_bounds__(512, 1) void lstm_mfma6(
    const float* __restrict__ data, const float* __restrict__ W_ih,
    const float* __restrict__ W_hh, const float* __restrict__ b_ih,
    const float* __restrict__ b_hh, float* __restrict__ out)
{
    const int b   = blockIdx.x;
    const int t   = threadIdx.x;
    const int w   = t >> 6;
    const int l   = t & 63;
    const int col = l & 15;
    const int kg  = l >> 4;

    half8 bfh[4][4];
    half8 bfx[4][2];
    float bs[4];
#pragma unroll
    for (int g = 0; g < 4; ++g) {
        const float sc = (g == 2) ? -2.8853900817779268f : -1.4426950408889634f;
        const int row = 128 * g + 16 * w + col;
        bs[g] = sc * (b_ih[row] + b_hh[row]);
        const float* wh = W_hh + (size_t)row * Hh;
        const float* wi = W_ih + (size_t)row * Ii;
#pragma unroll
        for (int s = 0; s < 4; ++s) {
            const float* src = wh + 32 * s + 8 * kg;
            const float4 f0 = ((const float4*)src)[0];
            const float4 f1 = ((const float4*)src)[1];
            H8U u;
            u.p[0] = pk16(sc * f0.x, sc * f0.y); u.p[1] = pk16(sc * f0.z, sc * f0.w);
            u.p[2] = pk16(sc * f1.x, sc * f1.y); u.p[3] = pk16(sc * f1.z, sc * f1.w);
            bfh[g][s] = u.v;
        }
#pragma unroll
        for (int s = 0; s < 2; ++s) {
            const float* src = wi + 32 * s + 8 * kg;
            const float4 f0 = ((const float4*)src)[0];
            const float4 f1 = ((const float4*)src)[1];
            H8U u;
            u.p[0] = pk16(sc * f0.x, sc * f0.y); u.p[1] = pk16(sc * f0.z, sc * f0.w);
            u.p[2] = pk16(sc * f1.x, sc * f1.y); u.p[3] = pk16(sc * f1.z, sc * f1.w);
            bfx[g][s] = u.v;
        }
    }

    __shared__ __align__(16) _Float16 hb[2][Hh];
    const float* xp  = data + (size_t)b * Tt * Ii;
    float*       opr = out  + (size_t)b * Tt * Hh + 16 * w + col;
    if (t < Hh) hb[0][t] = (_Float16)0.0f;

    const float* xbase = xp + (size_t)(l & 15) * Ii + 8 * kg;
    float4 xf0 = *(const float4*)(xbase);
    float4 xf1 = *(const float4*)(xbase + 4);
    float4 xf2 = *(const float4*)(xbase + 32);
    float4 xf3 = *(const float4*)(xbase + 36);

    half8 ax0 = cvt8(xf0, xf1);
    half8 ax1 = cvt8(xf2, xf3);
    xf0 = *(const float4*)(xbase + CH * Ii);
    xf1 = *(const float4*)(xbase + CH * Ii + 4);
    xf2 = *(const float4*)(xbase + CH * Ii + 32);
    xf3 = *(const float4*)(xbase + CH * Ii + 36);
    floatx4 xw0 = MFMA16(ax0, bfx[0][0], splat4(bs[0]));
    floatx4 xw1 = MFMA16(ax0, bfx[1][0], splat4(bs[1]));
    floatx4 xw2 = MFMA16(ax0, bfx[2][0], splat4(bs[2]));
    floatx4 xw3 = MFMA16(ax0, bfx[3][0], splat4(bs[3]));
    xw0 = MFMA16(ax1, bfx[0][1], xw0);
    xw1 = MFMA16(ax1, bfx[1][1], xw1);
    xw2 = MFMA16(ax1, bfx[2][1], xw2);
    xw3 = MFMA16(ax1, bfx[3][1], xw3);

    half8 nax0, nax1;
    floatx4 nxw0, nxw1, nxw2, nxw3;

    float c = 0.0f;
    __syncthreads();

#pragma unroll 1
    for (int n = 0; n < NCH; ++n) {
        const float* xb2 = xbase + (size_t)((n + 2 < NCH) ? n + 2 : NCH - 1) * CH * Ii;

#define STEP(P, R, CUR, XTRA)                                                 \
        {                                                                     \
            const _Float16* hbase = &hb[CUR][8 * kg];                         \
            const half8 ah0 = *(const half8*)(hbase);                         \
            const half8 ah1 = *(const half8*)(hbase + 32);                    \
            const half8 ah2 = *(const half8*)(hbase + 64);                    \
            const half8 ah3 = *(const half8*)(hbase + 96);                    \
            XTRA;                                                             \
            __builtin_amdgcn_s_setprio(1);                                    \
            floatx4 qf = MFMA16(ah0, bfh[1][0], xw1);                         \
            floatx4 qg = MFMA16(ah0, bfh[2][0], xw2);                         \
            floatx4 qi = MFMA16(ah0, bfh[0][0], xw0);                         \
            qf = MFMA16(ah1, bfh[1][1], qf);                                  \
            qg = MFMA16(ah1, bfh[2][1], qg);                                  \
            qi = MFMA16(ah1, bfh[0][1], qi);                                  \
            floatx4 qo = MFMA16(ah0, bfh[3][0], xw3);                         \
            qf = MFMA16(ah2, bfh[1][2], qf);                                  \
            qg = MFMA16(ah2, bfh[2][2], qg);                                  \
            qi = MFMA16(ah2, bfh[0][2], qi);                                  \
            qo = MFMA16(ah1, bfh[3][1], qo);                                  \
            qf = MFMA16(ah3, bfh[1][3], qf);                                  \
            qg = MFMA16(ah3, bfh[2][3], qg);                                  \
            qi = MFMA16(ah3, bfh[0][3], qi);                                  \
            qo = MFMA16(ah2, bfh[3][2], qo);                                  \
            const float fg = fast_rcp(1.0f + exp2_(qf[R]));                   \
            const float eg = exp2_(qg[R]);                                    \
            const float fc = fg * c;                                          \
            const float gv = (1.0f - eg) * fast_rcp(1.0f + eg);               \
            const float ig = fast_rcp(1.0f + exp2_(qi[R]));                   \
            c = fmaf(ig, gv, fc);                                             \
            const float ec = exp2_(-2.8853900817779268f * c);                 \
            const float tc = (1.0f - ec) * fast_rcp(1.0f + ec);               \
            qo = MFMA16(ah3, bfh[3][3], qo);                                  \
            __builtin_amdgcn_s_setprio(0);                                    \
            const float og = fast_rcp(1.0f + exp2_(qo[R]));                   \
            const float h  = og * tc;                                         \
            if (kg == (P)) {                                                  \
                hb[(CUR) ^ 1][16 * w + col] = (_Float16)h;                    \
                *opr = h;                                                     \
            }                                                                 \
            opr += Hh;                                                        \
            asm volatile("s_waitcnt lgkmcnt(0)\n\ts_barrier" ::: "memory");   \
        }

#define PHASE(P, X0, X1, X2, X3)                                              \
        STEP(P, 0, 0, X0) STEP(P, 1, 1, X1) STEP(P, 2, 0, X2) STEP(P, 3, 1, X3)

        PHASE(0,
              (c = __shfl(c, (l + 48) & 63), nax0 = cvt8(xf0, xf1)),
              nax1 = cvt8(xf2, xf3),
              nxw0 = MFMA16(nax0, bfx[0][0], splat4(bs[0])),
              nxw1 = MFMA16(nax0, bfx[1][0], splat4(bs[1])))
        PHASE(1,
              (c = __shfl(c, (l + 48) & 63), nxw2 = MFMA16(nax0, bfx[2][0], splat4(bs[2]))),
              nxw3 = MFMA16(nax0, bfx[3][0], splat4(bs[3])),
              nxw0 = MFMA16(nax1, bfx[0][1], nxw0),
              nxw1 = MFMA16(nax1, bfx[1][1], nxw1))
        PHASE(2,
              (c = __shfl(c, (l + 48) & 63), nxw2 = MFMA16(nax1, bfx[2][1], nxw2)),
              nxw3 = MFMA16(nax1, bfx[3][1], nxw3),
              xf0 = *(const float4*)(xb2),
              xf1 = *(const float4*)(xb2 + 4))
        PHASE(3,
              (c = __shfl(c, (l + 48) & 63), xf2 = *(const float4*)(xb2 + 32)),
              xf3 = *(const float4*)(xb2 + 36),
              (void)0,
              (void)0)
#undef PHASE
#undef STEP

        xw0 = nxw0; xw1 = nxw1; xw2 = nxw2; xw3 = nxw3;
    }
}

extern "C" void kernel_launch(void* const* d_in, const int* in_sizes, int n_in,
                              void* d_out, int out_size, void* d_ws, size_t ws_size,
                              hipStream_t stream) {
    const float* data = (const float*)d_in[0];
    const float* W_ih = (const float*)d_in[1];
    const float* W_hh = (const float*)d_in[2];
    const float* b_ih = (const float*)d_in[3];
    const float* b_hh = (const float*)d_in[4];
    float* out = (float*)d_out;

    const size_t need = (size_t)256 * NCH * 512 * 16 * sizeof(_Float16); // 268435456
    if (d_ws != nullptr && ws_size >= need) {
        hipLaunchKernelGGL(lstm_ws16, dim3(256), dim3(512), 0, stream,
                           data, W_ih, W_hh, b_ih, b_hh, out, (_Float16*)d_ws);
    } else {
        hipLaunchKernelGGL(lstm_mfma6, dim3(256), dim3(512), 0, stream,
                           data, W_ih, W_hh, b_ih, b_hh, out);
    }
}